// Round 14
// baseline (297.162 us; speedup 1.0000x reference)
//
#include <hip/hip_runtime.h>
#include <hip/hip_bf16.h>

// Problem constants: B=2, S=2048, DIM=2048, H=16, KVH=8, D=128

typedef __attribute__((ext_vector_type(8))) short s16x8;   // 8 bf16 in 4 VGPRs
typedef __attribute__((ext_vector_type(4))) float f32x4;
typedef __attribute__((ext_vector_type(16))) float f32x16;

typedef const __attribute__((address_space(1))) void* gas_t;
typedef __attribute__((address_space(3))) void* las_t;
#define GLL16(g, l) __builtin_amdgcn_global_load_lds((gas_t)(const void*)(g), (las_t)(void*)(l), 16, 0, 0)

static __device__ __forceinline__ unsigned short f2bf(float f) {
    union { float f; unsigned u; } v; v.f = f;
    unsigned r = v.u + 0x7FFF + ((v.u >> 16) & 1);   // RNE
    return (unsigned short)(r >> 16);
}
static __device__ __forceinline__ float bf2f(unsigned short h) {
    union { unsigned u; float f; } v; v.u = ((unsigned)h) << 16;
    return v.f;
}
static __device__ __forceinline__ float exp2_fast(float x) {
    float r; asm("v_exp_f32 %0, %1" : "=v"(r) : "v"(x)); return r;
}
static __device__ __forceinline__ unsigned cvt_pk_bf16(float a, float b) {
    unsigned r; asm("v_cvt_pk_bf16_f32 %0, %1, %2" : "=v"(r) : "v"(a), "v"(b)); return r;
}

// scale(1/sqrt(128)) * log2(e): baked into Q so softmax runs in exp2 domain
#define SCALE_L2E 0.12751744900929f

// ---------------- f32 -> bf16 elementwise convert (x) ----------------
__global__ __launch_bounds__(256) void k_convert_x(const float* __restrict__ x,
                                                   unsigned short* __restrict__ xb, int n) {
    int i = (blockIdx.x * 256 + threadIdx.x) * 8;
    if (i >= n) return;
    float4 a = *(const float4*)(x + i);
    float4 b = *(const float4*)(x + i + 4);
    s16x8 o;
    o[0] = (short)f2bf(a.x); o[1] = (short)f2bf(a.y); o[2] = (short)f2bf(a.z); o[3] = (short)f2bf(a.w);
    o[4] = (short)f2bf(b.x); o[5] = (short)f2bf(b.y); o[6] = (short)f2bf(b.z); o[7] = (short)f2bf(b.w);
    *(s16x8*)(xb + i) = o;
}

// ---------------- weight transpose f32 (K x N) -> bf16 (N x K) ----------------
__global__ __launch_bounds__(256) void k_transpose_w(const float* __restrict__ src,
                                                     unsigned short* __restrict__ dst,
                                                     int K, int N, int nbase, int dstld) {
    __shared__ float t[32][33];
    int k0 = blockIdx.x * 32, n0 = blockIdx.y * 32;
    int tx = threadIdx.x & 31, ty0 = threadIdx.x >> 5;
    for (int p = 0; p < 4; p++) {
        int ty = ty0 + p * 8;
        t[ty][tx] = src[(size_t)(k0 + ty) * N + n0 + tx];
    }
    __syncthreads();
    for (int p = 0; p < 4; p++) {
        int ty = ty0 + p * 8;
        dst[(size_t)(nbase + n0 + ty) * dstld + k0 + tx] = f2bf(t[tx][ty]);
    }
}

// ---------------- bf16 transpose: V (2048 x 128) -> Vt (128 x 2048), per (b,kvh) ----------------
__global__ __launch_bounds__(256) void k_transpose_v(const unsigned short* __restrict__ V,
                                                     unsigned short* __restrict__ Vt) {
    __shared__ unsigned short t[32][33];
    int s0 = blockIdx.x * 32, d0 = blockIdx.y * 32;
    size_t base = (size_t)blockIdx.z * 2048 * 128;
    int tx = threadIdx.x & 31, ty0 = threadIdx.x >> 5;
    for (int p = 0; p < 4; p++) {
        int ty = ty0 + p * 8;
        t[ty][tx] = V[base + (size_t)(s0 + ty) * 128 + d0 + tx];
    }
    __syncthreads();
    for (int p = 0; p < 4; p++) {
        int ty = ty0 + p * 8;
        Vt[base + (size_t)(d0 + ty) * 2048 + s0 + tx] = t[tx][ty];
    }
}

// ---------------- 256x256 GEMM v5 (unchanged from R12: conflict-free swizzle) ----------------
template<int OUTF32>
__global__ __launch_bounds__(512, 2) void k_gemm256(const unsigned short* __restrict__ A,
                                                    const unsigned short* __restrict__ Bt,
                                                    void* __restrict__ Cout,
                                                    int M, int N, int K) {
    __shared__ unsigned short Ls[2][2][2][8192];   // [slot][mat A=0/B=1][kk][256*32] = 128 KiB
    int tid = threadIdx.x, lane = tid & 63, wave = tid >> 6;
    int wm = wave >> 2, wn = wave & 3;
    int lr = lane & 15, lg = lane >> 4;
    int swrow = wave * 16 + (lane >> 2);                   // staging row within 128-row half
    int scol  = (((lane & 3) ^ ((lane >> 3) & 3)) * 8);    // pre-swizzled source col (elems)
    int cg    = ((lg ^ ((lr >> 1) & 3)) * 8);              // swizzled read col (elems)
    const unsigned short* Ab = A  + (size_t)(blockIdx.x * 256) * K;
    const unsigned short* Bb = Bt + (size_t)(blockIdx.y * 256) * K;

    f32x4 acc[8][4] = {};
    int NK = K / 64;

    auto issue = [&](int slot, int mat, int kk, int k0) {
        const unsigned short* base = mat ? Bb : Ab;
        unsigned short* dst = &Ls[slot][mat][kk][wave * 512];
        GLL16(base + (size_t)swrow * K + k0 + kk * 32 + scol, dst);
        GLL16(base + (size_t)(swrow + 128) * K + k0 + kk * 32 + scol, dst + 4096);
    };

    issue(0, 0, 0, 0);
    issue(0, 1, 0, 0);
    issue(0, 0, 1, 0);
    issue(0, 1, 1, 0);
    asm volatile("s_waitcnt vmcnt(4)" ::: "memory");
    __builtin_amdgcn_s_barrier();

    for (int t = 0; t < NK; ++t) {
        int slot = t & 1, nslot = slot ^ 1;
        int kn = (t + 1) * 64;
        bool more = (t + 1) < NK;
        const unsigned short* As0 = Ls[slot][0][0];
        const unsigned short* Bs0 = Ls[slot][1][0];
        const unsigned short* As1 = Ls[slot][0][1];
        const unsigned short* Bs1 = Ls[slot][1][1];
        s16x8 af[4], bfr[4];

        // ---- phase 0: kk0, m0-3 ----
        #pragma unroll
        for (int m = 0; m < 4; m++) af[m]  = *(const s16x8*)&As0[(wm * 128 + m * 16 + lr) * 32 + cg];
        #pragma unroll
        for (int n = 0; n < 4; n++) bfr[n] = *(const s16x8*)&Bs0[(wn * 64 + n * 16 + lr) * 32 + cg];
        if (more) issue(nslot, 0, 0, kn);
        asm volatile("" ::: "memory");
        __builtin_amdgcn_s_barrier();
        __builtin_amdgcn_s_setprio(1);
        #pragma unroll
        for (int m = 0; m < 4; m++)
            #pragma unroll
            for (int n = 0; n < 4; n++)
                acc[m][n] = __builtin_amdgcn_mfma_f32_16x16x32_bf16(af[m], bfr[n], acc[m][n], 0, 0, 0);
        __builtin_amdgcn_s_setprio(0);
        asm volatile("" ::: "memory");
        __builtin_amdgcn_s_barrier();

        // ---- phase 1: kk0, m4-7 ----
        #pragma unroll
        for (int m = 0; m < 4; m++) af[m] = *(const s16x8*)&As0[(wm * 128 + (m + 4) * 16 + lr) * 32 + cg];
        if (more) { issue(nslot, 1, 0, kn); asm volatile("s_waitcnt vmcnt(4)" ::: "memory"); }
        else      {                         asm volatile("s_waitcnt vmcnt(0)" ::: "memory"); }
        asm volatile("" ::: "memory");
        __builtin_amdgcn_s_barrier();
        __builtin_amdgcn_s_setprio(1);
        #pragma unroll
        for (int m = 0; m < 4; m++)
            #pragma unroll
            for (int n = 0; n < 4; n++)
                acc[m + 4][n] = __builtin_amdgcn_mfma_f32_16x16x32_bf16(af[m], bfr[n], acc[m + 4][n], 0, 0, 0);
        __builtin_amdgcn_s_setprio(0);
        asm volatile("" ::: "memory");
        __builtin_amdgcn_s_barrier();

        // ---- phase 2: kk1, m0-3 ----
        #pragma unroll
        for (int m = 0; m < 4; m++) af[m]  = *(const s16x8*)&As1[(wm * 128 + m * 16 + lr) * 32 + cg];
        #pragma unroll
        for (int n = 0; n < 4; n++) bfr[n] = *(const s16x8*)&Bs1[(wn * 64 + n * 16 + lr) * 32 + cg];
        if (more) issue(nslot, 0, 1, kn);
        asm volatile("" ::: "memory");
        __builtin_amdgcn_s_barrier();
        __builtin_amdgcn_s_setprio(1);
        #pragma unroll
        for (int m = 0; m < 4; m++)
            #pragma unroll
            for (int n = 0; n < 4; n++)
                acc[m][n] = __builtin_amdgcn_mfma_f32_16x16x32_bf16(af[m], bfr[n], acc[m][n], 0, 0, 0);
        __builtin_amdgcn_s_setprio(0);
        asm volatile("" ::: "memory");
        __builtin_amdgcn_s_barrier();

        // ---- phase 3: kk1, m4-7 ----
        #pragma unroll
        for (int m = 0; m < 4; m++) af[m] = *(const s16x8*)&As1[(wm * 128 + (m + 4) * 16 + lr) * 32 + cg];
        if (more) { issue(nslot, 1, 1, kn); asm volatile("s_waitcnt vmcnt(4)" ::: "memory"); }
        asm volatile("" ::: "memory");
        __builtin_amdgcn_s_barrier();
        __builtin_amdgcn_s_setprio(1);
        #pragma unroll
        for (int m = 0; m < 4; m++)
            #pragma unroll
            for (int n = 0; n < 4; n++)
                acc[m + 4][n] = __builtin_amdgcn_mfma_f32_16x16x32_bf16(af[m], bfr[n], acc[m + 4][n], 0, 0, 0);
        __builtin_amdgcn_s_setprio(0);
        asm volatile("" ::: "memory");
        __builtin_amdgcn_s_barrier();
    }

    int rbase = blockIdx.x * 256 + wm * 128;
    int cbase = blockIdx.y * 256 + wn * 64;
    #pragma unroll
    for (int am = 0; am < 8; am++)
        #pragma unroll
        for (int n = 0; n < 4; n++)
            #pragma unroll
            for (int r = 0; r < 4; r++) {
                int row = rbase + am * 16 + lg * 4 + r;
                int col = cbase + n * 16 + lr;
                float v = acc[am][n][r];
                if (OUTF32) ((float*)Cout)[(size_t)row * N + col] = v;
                else        ((unsigned short*)Cout)[(size_t)row * N + col] = f2bf(v);
            }
}

// ---------------- GEMM: 128x128 m97 structure (kept for gemm2, N=2048) ----------------
template<int OUTF32>
__global__ __launch_bounds__(256) void k_gemm_bt(const unsigned short* __restrict__ A,
                                                 const unsigned short* __restrict__ Bt,
                                                 void* __restrict__ Cout,
                                                 int M, int N, int K) {
    __shared__ unsigned short As[128 * 32];
    __shared__ unsigned short Bs[128 * 32];
    int tid = threadIdx.x;
    int lane = tid & 63;
    int wave = tid >> 6;
    int wm = wave >> 1, wn = wave & 1;
    int lr = lane & 15, lk = (lane >> 4) * 8;
    int srow = wave * 32 + (lane >> 2);
    int scol = (lane & 3) * 8;
    const unsigned short* Ag0 = A  + (size_t)(blockIdx.x * 128 + srow) * K + scol;
    const unsigned short* Ag1 = Ag0 + (size_t)16 * K;
    const unsigned short* Bg0 = Bt + (size_t)(blockIdx.y * 128 + srow) * K + scol;
    const unsigned short* Bg1 = Bg0 + (size_t)16 * K;
    unsigned short* Asw = &As[wave * 1024];
    unsigned short* Bsw = &Bs[wave * 1024];
    f32x4 acc[4][4] = {};
    for (int k0 = 0; k0 < K; k0 += 32) {
        __syncthreads();
        GLL16(Ag0 + k0, Asw);
        GLL16(Ag1 + k0, Asw + 512);
        GLL16(Bg0 + k0, Bsw);
        GLL16(Bg1 + k0, Bsw + 512);
        __syncthreads();
        s16x8 af[4], bfr[4];
        #pragma unroll
        for (int m = 0; m < 4; m++) af[m]  = *(const s16x8*)&As[(wm * 64 + m * 16 + lr) * 32 + lk];
        #pragma unroll
        for (int n = 0; n < 4; n++) bfr[n] = *(const s16x8*)&Bs[(wn * 64 + n * 16 + lr) * 32 + lk];
        #pragma unroll
        for (int m = 0; m < 4; m++)
            #pragma unroll
            for (int n = 0; n < 4; n++)
                acc[m][n] = __builtin_amdgcn_mfma_f32_16x16x32_bf16(af[m], bfr[n], acc[m][n], 0, 0, 0);
    }
    int rbase = blockIdx.x * 128 + wm * 64;
    int cbase = blockIdx.y * 128 + wn * 64;
    #pragma unroll
    for (int m = 0; m < 4; m++)
        #pragma unroll
        for (int n = 0; n < 4; n++)
            #pragma unroll
            for (int r = 0; r < 4; r++) {
                int row = rbase + m * 16 + (lane >> 4) * 4 + r;
                int col = cbase + n * 16 + lr;
                float v = acc[m][n][r];
                if (OUTF32) ((float*)Cout)[(size_t)row * N + col] = v;
                else        ((unsigned short*)Cout)[(size_t)row * N + col] = f2bf(v);
            }
}

// ---------------- fused RMSNorm + RoPE + head transpose (vectorized) ----------------
__global__ __launch_bounds__(256) void k_rms_rope(const unsigned short* __restrict__ qkv,
                                                  const float* __restrict__ qg,
                                                  const float* __restrict__ kg,
                                                  const float* __restrict__ cosc,
                                                  const float* __restrict__ sinc,
                                                  unsigned short* __restrict__ Qt,
                                                  unsigned short* __restrict__ Kt,
                                                  unsigned short* __restrict__ Vt) {
    int r = blockIdx.x;            // b*2048 + s
    int b = r >> 11;
    int s = r & 2047;
    int tid = threadIdx.x;
    int wave = tid >> 6, lane = tid & 63;
    int sl = lane >> 4;            // local segment 0..3
    int li = lane & 15;
    int d0 = li * 8;               // 0..120
    const unsigned short* row = qkv + (size_t)r * 4096;
    #pragma unroll
    for (int p = 0; p < 2; p++) {
        int seg = p * 16 + wave * 4 + sl;   // 0..31, wave-uniform type
        s16x8 raw = *(const s16x8*)(row + seg * 128 + d0);
        if (seg >= 24) {   // V: straight copy (wave-uniform branch)
            *(s16x8*)(Vt + ((size_t)(b * 8 + (seg - 24)) * 2048 + s) * 128 + d0) = raw;
            continue;
        }
        float e[8];
        #pragma unroll
        for (int j = 0; j < 8; j++) e[j] = bf2f((unsigned short)raw[j]);
        float ssq = 0.f;
        #pragma unroll
        for (int j = 0; j < 8; j++) ssq += e[j] * e[j];
        ssq += __shfl_xor(ssq, 1, 64);
        ssq += __shfl_xor(ssq, 2, 64);
        ssq += __shfl_xor(ssq, 4, 64);
        ssq += __shfl_xor(ssq, 8, 64);
        float rn = rsqrtf(ssq * (1.0f / 128.0f) + 1e-6f);
        const float* g = (seg < 16) ? qg : kg;
        float gs = (seg < 16) ? SCALE_L2E : 1.0f;
        float4 g0 = *(const float4*)(g + d0);
        float4 g1 = *(const float4*)(g + d0 + 4);
        float t[8];
        t[0] = e[0] * rn * g0.x * gs; t[1] = e[1] * rn * g0.y * gs;
        t[2] = e[2] * rn * g0.z * gs; t[3] = e[3] * rn * g0.w * gs;
        t[4] = e[4] * rn * g1.x * gs; t[5] = e[5] * rn * g1.y * gs;
        t[6] = e[6] * rn * g1.z * gs; t[7] = e[7] * rn * g1.w * gs;
        float pr[8];
        #pragma unroll
        for (int j = 0; j < 8; j++) pr[j] = __shfl_xor(t[j], 8, 64);
        int didx = d0 & 63;
        float4 c0 = *(const float4*)(cosc + (size_t)s * 64 + didx);
        float4 c1 = *(const float4*)(cosc + (size_t)s * 64 + didx + 4);
        float4 sn0 = *(const float4*)(sinc + (size_t)s * 64 + didx);
        float4 sn1 = *(const float4*)(sinc + (size_t)s * 64 + didx + 4);
        float cv[8] = {c0.x, c0.y, c0.z, c0.w, c1.x, c1.y, c1.z, c1.w};
        float sv[8] = {sn0.x, sn0.y, sn0.z, sn0.w, sn1.x, sn1.y, sn1.z, sn1.w};
        float sgn = (li < 8) ? -1.0f : 1.0f;
        s16x8 o;
        #pragma unroll
        for (int j = 0; j < 8; j++)
            o[j] = (short)f2bf(t[j] * cv[j] + sgn * pr[j] * sv[j]);
        unsigned short* dst = (seg < 16)
            ? Qt + ((size_t)(b * 16 + seg) * 2048 + s) * 128 + d0
            : Kt + ((size_t)(b * 8 + (seg - 16)) * 2048 + s) * 128 + d0;
        *(s16x8*)dst = o;
    }
}

// ---------------- causal GQA flash attention: LDS-free, global-frag version ----------------
// 1 wave per block (64 thr), 32 q-rows/wave, KVBLK=64, grid 2048 = 8 blocks/CU.
// K and V^T fragments loaded DIRECTLY from global (L1/L2-resident: 1 MB per
// (b,kvh); block->XCD mapping pins <=2 KV sets per XCD). K double-buffered in
// regs (prefetch lands under softmax+PV); V in two 8-frag halves. Only the
// per-wave P tile goes through LDS -> zero barriers, zero cross-wave LDS traffic.
__global__ __launch_bounds__(64, 2) void k_attn(const unsigned short* __restrict__ Qt,
                                                const unsigned short* __restrict__ Kt,
                                                const unsigned short* __restrict__ Vtg,
                                                unsigned short* __restrict__ attn) {
    __shared__ unsigned short Ps[32][72];   // per-block P tile [q][kv], padded
    int bid = blockIdx.x;                  // 0..2047
    // XCD-aware layout: x = XCD (dispatch round-robin), l = per-XCD index.
    // CU class (l mod 32) fixes bh -> all 8 blocks on a CU share one KV set;
    // alternating-direction qc pairing balances causal work per class.
    int x = bid & 7, l = bid >> 3;         // l: 0..255
    int bh = x * 4 + (l & 3);              // 0..31
    int cc = (l >> 2) & 7, j = l >> 5;     // cc: 0..7, j: 0..7
    int qc = j * 8 + ((j & 1) ? (7 - cc) : cc);   // 0..63, per-class-balanced
    int b = bh >> 4, h = bh & 15;
    int kvh = h >> 1;
    int lane = threadIdx.x;
    int ql = lane & 31;                    // q-local
    int hf = lane >> 5;                    // half 0/1
    int q0 = qc * 32;
    const unsigned short* Qb    = Qt + ((size_t)bh * 2048 + q0 + ql) * 128;
    const unsigned short* Kbase = Kt + (size_t)(b * 8 + kvh) * 2048 * 128;
    const unsigned short* Vtb   = Vtg + (size_t)(b * 8 + kvh) * 128 * 2048;   // [d][s]
    s16x8 aq[8];
    #pragma unroll
    for (int ds = 0; ds < 8; ds++)
        aq[ds] = *(const s16x8*)(Qb + ds * 16 + hf * 8);
    f32x16 out[4] = {};
    float m_q = -1e30f, l_q = 0.f;
    int qglob = q0 + ql;
    int ntiles = (qc >> 1) + 1;
    // prologue: K tile 0 into regs (frag (sub,ds) = K[sub*32+ql][ds*16+hf*8..+7])
    s16x8 kreg[16];
    #pragma unroll
    for (int sub = 0; sub < 2; sub++)
        #pragma unroll
        for (int ds = 0; ds < 8; ds++)
            kreg[sub * 8 + ds] = *(const s16x8*)(Kbase + (size_t)(sub * 32 + ql) * 128 + ds * 16 + hf * 8);

    for (int t = 0; t < ntiles; t++) {
        int k0 = t * 64;
        // QK^T (swapped): S^T[kv][q], A = K frags, B = Q
        f32x16 st[2] = {};
        __builtin_amdgcn_s_setprio(1);
        #pragma unroll
        for (int sub = 0; sub < 2; sub++)
            #pragma unroll
            for (int ds = 0; ds < 8; ds++)
                st[sub] = __builtin_amdgcn_mfma_f32_32x32x16_bf16(kreg[sub * 8 + ds], aq[ds], st[sub], 0, 0, 0);
        __builtin_amdgcn_s_setprio(0);
        // prefetch K(t+1) -> lands under softmax + PV
        if (t + 1 < ntiles) {
            int kn = k0 + 64;
            #pragma unroll
            for (int sub = 0; sub < 2; sub++)
                #pragma unroll
                for (int ds = 0; ds < 8; ds++)
                    kreg[sub * 8 + ds] = *(const s16x8*)(Kbase + (size_t)(kn + sub * 32 + ql) * 128 + ds * 16 + hf * 8);
        }
        // V first half (ks 0,1) -> lands under softmax
        s16x8 vA[8];
        #pragma unroll
        for (int ks = 0; ks < 2; ks++)
            #pragma unroll
            for (int dblk = 0; dblk < 4; dblk++)
                vA[ks * 4 + dblk] = *(const s16x8*)(Vtb + (size_t)(dblk * 32 + ql) * 2048 + k0 + ks * 16 + hf * 8);
        // softmax: lane holds 32 S values of q-row qglob at kv = k0+sub*32+(r&3)+8*(r>>2)+4*hf
        float mx = -1e30f;
        if (k0 + 63 > q0) {   // boundary tiles: apply causal mask
            #pragma unroll
            for (int sub = 0; sub < 2; sub++)
                #pragma unroll
                for (int r = 0; r < 16; r++) {
                    int kv = k0 + sub * 32 + (r & 3) + 8 * (r >> 2) + 4 * hf;
                    if (kv > qglob) st[sub][r] = -1e30f;
                    mx = fmaxf(mx, st[sub][r]);
                }
        } else {
            #pragma unroll
            for (int sub = 0; sub < 2; sub++)
                #pragma unroll
                for (int r = 0; r < 16; r++) mx = fmaxf(mx, st[sub][r]);
        }
        mx = fmaxf(mx, __shfl_xor(mx, 32, 64));
        bool defer = __all(mx <= m_q + 8.0f);
        float sf = 1.0f;
        if (!defer) {
            float mnew = fmaxf(m_q, mx);
            sf = exp2_fast(m_q - mnew);
            m_q = mnew;
        }
        float rs = 0.f;
        #pragma unroll
        for (int sub = 0; sub < 2; sub++)
            #pragma unroll
            for (int r = 0; r < 16; r++) {
                float e = exp2_fast(st[sub][r] - m_q);
                st[sub][r] = e;
                rs += e;
            }
        rs += __shfl_xor(rs, 32, 64);
        l_q = defer ? (l_q + rs) : (l_q * sf + rs);
        // pack P -> Ps[q][kv] via cvt_pk (group g: kv = sub*32 + g*8 + hf*4 .. +3)
        #pragma unroll
        for (int sub = 0; sub < 2; sub++)
            #pragma unroll
            for (int g = 0; g < 4; g++) {
                uint2 w;
                w.x = cvt_pk_bf16(st[sub][4 * g + 0], st[sub][4 * g + 1]);
                w.y = cvt_pk_bf16(st[sub][4 * g + 2], st[sub][4 * g + 3]);
                *(uint2*)&Ps[ql][sub * 32 + g * 8 + hf * 4] = w;
            }
        // V second half (ks 2,3) -> lands under rescale + PV ks01
        s16x8 vB[8];
        #pragma unroll
        for (int ks = 0; ks < 2; ks++)
            #pragma unroll
            for (int dblk = 0; dblk < 4; dblk++)
                vB[ks * 4 + dblk] = *(const s16x8*)(Vtb + (size_t)(dblk * 32 + ql) * 2048 + k0 + (ks + 2) * 16 + hf * 8);
        if (!defer) {
            float sfr[16];
            #pragma unroll
            for (int r = 0; r < 16; r++)
                sfr[r] = __shfl(sf, (r & 3) + 8 * (r >> 2) + 4 * hf, 64);
            #pragma unroll
            for (int dblk = 0; dblk < 4; dblk++)
                #pragma unroll
                for (int r = 0; r < 16; r++) out[dblk][r] *= sfr[r];
        }
        // PV: O += P(32x64) V(64x128); A-frag lane = P[q=ql][kv=ks*16+hf*8..+7]
        __builtin_amdgcn_s_setprio(1);
        #pragma unroll
        for (int ks = 0; ks < 2; ks++) {
            s16x8 pf = *(const s16x8*)&Ps[ql][ks * 16 + hf * 8];
            #pragma unroll
            for (int dblk = 0; dblk < 4; dblk++)
                out[dblk] = __builtin_amdgcn_mfma_f32_32x32x16_bf16(pf, vA[ks * 4 + dblk], out[dblk], 0, 0, 0);
        }
        #pragma unroll
        for (int ks = 0; ks < 2; ks++) {
            s16x8 pf = *(const s16x8*)&Ps[ql][(ks + 2) * 16 + hf * 8];
            #pragma unroll
            for (int dblk = 0; dblk < 4; dblk++)
                out[dblk] = __builtin_amdgcn_mfma_f32_32x32x16_bf16(pf, vB[ks * 4 + dblk], out[dblk], 0, 0, 0);
        }
        __builtin_amdgcn_s_setprio(0);
    }
    float linv = 1.0f / l_q;
    float inv[16];
    #pragma unroll
    for (int r = 0; r < 16; r++)
        inv[r] = __shfl(linv, (r & 3) + 8 * (r >> 2) + 4 * hf, 64);
    #pragma unroll
    for (int dblk = 0; dblk < 4; dblk++)
        #pragma unroll
        for (int r = 0; r < 16; r++) {
            int row = q0 + (r & 3) + 8 * (r >> 2) + 4 * hf;
            attn[((size_t)(b * 2048) + row) * 2048 + h * 128 + dblk * 32 + ql] =
                f2bf(out[dblk][r] * inv[r]);
        }
}

extern "C" void kernel_launch(void* const* d_in, const int* in_sizes, int n_in,
                              void* d_out, int out_size, void* d_ws, size_t ws_size,
                              hipStream_t stream) {
    const float* x    = (const float*)d_in[0];
    const float* wq   = (const float*)d_in[1];
    const float* wk   = (const float*)d_in[2];
    const float* wv   = (const float*)d_in[3];
    const float* wo   = (const float*)d_in[4];
    const float* qg   = (const float*)d_in[5];
    const float* kg   = (const float*)d_in[6];
    const float* cosc = (const float*)d_in[7];
    const float* sinc = (const float*)d_in[8];

    char* ws = (char*)d_ws;
    unsigned short* xb   = (unsigned short*)(ws);                 // 16 MiB  x bf16 (4096x2048)
    unsigned short* w1t  = (unsigned short*)(ws + 16777216);      // 16 MiB  [wq|wk|wv]^T (4096x2048)
    unsigned short* w2t  = (unsigned short*)(ws + 33554432);      //  8 MiB  wo^T (2048x2048)
    unsigned short* qkv  = (unsigned short*)(ws + 41943040);      // 32 MiB  (4096x4096); dead after k_rms_rope
    unsigned short* Qt   = (unsigned short*)(ws + 75497472);      // 16 MiB  (2,16,2048,128)
    unsigned short* Kt   = (unsigned short*)(ws + 92274688);      //  8 MiB  (2,8,2048,128)
    unsigned short* Vt   = (unsigned short*)(ws + 100663296);     //  8 MiB  (2,8,2048,128)
    unsigned short* attn = (unsigned short*)(ws + 109051904);     // 16 MiB  (4096x2048)
    unsigned short* Vtg  = qkv;                                   //  8 MiB  (2,8,128,2048) reuses qkv

    k_convert_x<<<4096, 256, 0, stream>>>(x, xb, 8388608);
    k_transpose_w<<<dim3(64, 64), 256, 0, stream>>>(wq, w1t, 2048, 2048, 0, 2048);
    k_transpose_w<<<dim3(64, 32), 256, 0, stream>>>(wk, w1t, 2048, 1024, 2048, 2048);
    k_transpose_w<<<dim3(64, 32), 256, 0, stream>>>(wv, w1t, 2048, 1024, 3072, 2048);
    k_transpose_w<<<dim3(64, 64), 256, 0, stream>>>(wo, w2t, 2048, 2048, 0, 2048);
    k_gemm256<0><<<dim3(16, 16), 512, 0, stream>>>(xb, w1t, qkv, 4096, 4096, 2048);
    k_rms_rope<<<4096, 256, 0, stream>>>(qkv, qg, kg, cosc, sinc, Qt, Kt, Vt);
    k_transpose_v<<<dim3(64, 4, 16), 256, 0, stream>>>(Vt, Vtg);
    k_attn<<<2048, 64, 0, stream>>>(Qt, Kt, Vtg, attn);
    k_gemm_bt<1><<<dim3(32, 16), 256, 0, stream>>>(attn, w2t, d_out, 4096, 2048, 2048);
}

// Round 15
// 223.229 us; speedup vs baseline: 1.3312x; 1.3312x over previous
//
#include <hip/hip_runtime.h>
#include <hip/hip_bf16.h>

// Problem constants: B=2, S=2048, DIM=2048, H=16, KVH=8, D=128

typedef __attribute__((ext_vector_type(8))) short s16x8;   // 8 bf16 in 4 VGPRs
typedef __attribute__((ext_vector_type(4))) float f32x4;
typedef __attribute__((ext_vector_type(16))) float f32x16;

typedef const __attribute__((address_space(1))) void* gas_t;
typedef __attribute__((address_space(3))) void* las_t;
#define GLL16(g, l) __builtin_amdgcn_global_load_lds((gas_t)(const void*)(g), (las_t)(void*)(l), 16, 0, 0)

static __device__ __forceinline__ unsigned short f2bf(float f) {
    union { float f; unsigned u; } v; v.f = f;
    unsigned r = v.u + 0x7FFF + ((v.u >> 16) & 1);   // RNE
    return (unsigned short)(r >> 16);
}
static __device__ __forceinline__ float bf2f(unsigned short h) {
    union { unsigned u; float f; } v; v.u = ((unsigned)h) << 16;
    return v.f;
}
static __device__ __forceinline__ float exp2_fast(float x) {
    float r; asm("v_exp_f32 %0, %1" : "=v"(r) : "v"(x)); return r;
}
static __device__ __forceinline__ unsigned cvt_pk_bf16(float a, float b) {
    unsigned r; asm("v_cvt_pk_bf16_f32 %0, %1, %2" : "=v"(r) : "v"(a), "v"(b)); return r;
}

// scale(1/sqrt(128)) * log2(e): baked into Q so softmax runs in exp2 domain
#define SCALE_L2E 0.12751744900929f

// ---------------- f32 -> bf16 elementwise convert (x) ----------------
__global__ __launch_bounds__(256) void k_convert_x(const float* __restrict__ x,
                                                   unsigned short* __restrict__ xb, int n) {
    int i = (blockIdx.x * 256 + threadIdx.x) * 8;
    if (i >= n) return;
    float4 a = *(const float4*)(x + i);
    float4 b = *(const float4*)(x + i + 4);
    s16x8 o;
    o[0] = (short)f2bf(a.x); o[1] = (short)f2bf(a.y); o[2] = (short)f2bf(a.z); o[3] = (short)f2bf(a.w);
    o[4] = (short)f2bf(b.x); o[5] = (short)f2bf(b.y); o[6] = (short)f2bf(b.z); o[7] = (short)f2bf(b.w);
    *(s16x8*)(xb + i) = o;
}

// ---------------- fused weight transpose: all four weights, one launch ----------------
// z selects source; f32 (K x N) -> bf16 (N x K) with nbase offset
__global__ __launch_bounds__(256) void k_transpose_w4(const float* __restrict__ wq,
                                                      const float* __restrict__ wk,
                                                      const float* __restrict__ wv,
                                                      const float* __restrict__ wo,
                                                      unsigned short* __restrict__ w1t,
                                                      unsigned short* __restrict__ w2t) {
    __shared__ float t[32][33];
    int z = blockIdx.z;
    const float* src; unsigned short* dst; int N, nbase;
    if (z == 0)      { src = wq; dst = w1t; N = 2048; nbase = 0;    }
    else if (z == 1) { src = wk; dst = w1t; N = 1024; nbase = 2048; }
    else if (z == 2) { src = wv; dst = w1t; N = 1024; nbase = 3072; }
    else             { src = wo; dst = w2t; N = 2048; nbase = 0;    }
    int k0 = blockIdx.x * 32, n0 = blockIdx.y * 32;
    if (n0 >= N) return;
    int tx = threadIdx.x & 31, ty0 = threadIdx.x >> 5;
    for (int p = 0; p < 4; p++) {
        int ty = ty0 + p * 8;
        t[ty][tx] = src[(size_t)(k0 + ty) * N + n0 + tx];
    }
    __syncthreads();
    for (int p = 0; p < 4; p++) {
        int ty = ty0 + p * 8;
        dst[(size_t)(nbase + n0 + ty) * 2048 + k0 + tx] = f2bf(t[tx][ty]);
    }
}

// ---------------- bf16 transpose: V (2048 x 128) -> Vt (128 x 2048), per (b,kvh) ----------------
__global__ __launch_bounds__(256) void k_transpose_v(const unsigned short* __restrict__ V,
                                                     unsigned short* __restrict__ Vt) {
    __shared__ unsigned short t[32][33];
    int s0 = blockIdx.x * 32, d0 = blockIdx.y * 32;
    size_t base = (size_t)blockIdx.z * 2048 * 128;
    int tx = threadIdx.x & 31, ty0 = threadIdx.x >> 5;
    for (int p = 0; p < 4; p++) {
        int ty = ty0 + p * 8;
        t[ty][tx] = V[base + (size_t)(s0 + ty) * 128 + d0 + tx];
    }
    __syncthreads();
    for (int p = 0; p < 4; p++) {
        int ty = ty0 + p * 8;
        Vt[base + (size_t)(d0 + ty) * 2048 + s0 + tx] = t[tx][ty];
    }
}

// ---------------- 256x256 GEMM v6: BK=32, 4-slot LDS ring, depth-8 pipeline ----------------
// 512 thr (8 waves 2Mx4N). Each BK=32 tile = A chunk (256x32) + B chunk (256x32),
// 4 GLLs. 4-slot ring (128 KiB): issue 3 tiles ahead; vmcnt retires tile t+1 with
// 8 loads in flight (issue->certify ~2 tiles > HBM latency). 2 barriers/tile:
// certification barrier (post-vmcnt) + trailing WAR barrier (reader's lgkm wait
// precedes it, writer's GLL follows it). Quad swizzle keeps ds_read conflict-free.
template<int OUTF32>
__global__ __launch_bounds__(512, 2) void k_gemm256(const unsigned short* __restrict__ A,
                                                    const unsigned short* __restrict__ Bt,
                                                    void* __restrict__ Cout,
                                                    int M, int N, int K) {
    __shared__ unsigned short Ls[4 * 2 * 8192];   // [ring][mat][256*32] = 128 KiB
    int tid = threadIdx.x, lane = tid & 63, wave = tid >> 6;
    int wm = wave >> 2, wn = wave & 3;
    int lr = lane & 15, lg = lane >> 4;
    int swrow = wave * 16 + (lane >> 2);                   // staging row within 128-row half
    int scol  = (((lane & 3) ^ ((lane >> 3) & 3)) * 8);    // pre-swizzled source col (elems)
    int cg    = ((lg ^ ((lr >> 1) & 3)) * 8);              // swizzled read col (elems)
    const unsigned short* Ab = A  + (size_t)(blockIdx.x * 256) * K;
    const unsigned short* Bb = Bt + (size_t)(blockIdx.y * 256) * K;

    f32x4 acc[8][4] = {};
    int NK = K / 32;   // requires NK >= 3

    auto issue = [&](int ring, int mat, int k0) {
        const unsigned short* base = mat ? Bb : Ab;
        unsigned short* dst = &Ls[(ring * 2 + mat) * 8192 + wave * 512];
        GLL16(base + (size_t)swrow * K + k0 + scol, dst);
        GLL16(base + (size_t)(swrow + 128) * K + k0 + scol, dst + 4096);
    };

    // prologue: tiles 0,1,2 staged (12 loads); certify tile 0 (keep 8 in flight)
    issue(0, 0, 0);  issue(0, 1, 0);
    issue(1, 0, 32); issue(1, 1, 32);
    issue(2, 0, 64); issue(2, 1, 64);
    asm volatile("s_waitcnt vmcnt(8)" ::: "memory");
    __builtin_amdgcn_s_barrier();
    asm volatile("" ::: "memory");

    for (int t = 0; t < NK; ++t) {
        int ring = t & 3;
        const unsigned short* As = &Ls[(ring * 2 + 0) * 8192];
        const unsigned short* Bs = &Ls[(ring * 2 + 1) * 8192];
        s16x8 af[4], bfr[4];
        // ph0 reads (tile t certified at t-1 + barrier)
        #pragma unroll
        for (int m = 0; m < 4; m++) af[m]  = *(const s16x8*)&As[(wm * 128 + m * 16 + lr) * 32 + cg];
        #pragma unroll
        for (int n = 0; n < 4; n++) bfr[n] = *(const s16x8*)&Bs[(wn * 64 + n * 16 + lr) * 32 + cg];
        // prefetch tile t+3 into ring (t+3)&3 (= ring (t-1)&3, reads done: see WAR proof)
        int rem = NK - 1 - t;
        if (rem >= 3) {
            int kn = (t + 3) * 32, rn = (t + 3) & 3;
            issue(rn, 0, kn); issue(rn, 1, kn);
        }
        // retire tile t+1 (certify for next iteration)
        if (rem >= 3)      asm volatile("s_waitcnt vmcnt(8)" ::: "memory");
        else if (rem == 2) asm volatile("s_waitcnt vmcnt(4)" ::: "memory");
        else if (rem == 1) asm volatile("s_waitcnt vmcnt(0)" ::: "memory");
        __builtin_amdgcn_s_barrier();
        asm volatile("" ::: "memory");
        __builtin_amdgcn_s_setprio(1);
        #pragma unroll
        for (int m = 0; m < 4; m++)
            #pragma unroll
            for (int n = 0; n < 4; n++)
                acc[m][n] = __builtin_amdgcn_mfma_f32_16x16x32_bf16(af[m], bfr[n], acc[m][n], 0, 0, 0);
        __builtin_amdgcn_s_setprio(0);
        // ph1 reads + MFMA (same tile, no cross-wave hazard)
        #pragma unroll
        for (int m = 0; m < 4; m++) af[m] = *(const s16x8*)&As[(wm * 128 + (m + 4) * 16 + lr) * 32 + cg];
        __builtin_amdgcn_s_setprio(1);
        #pragma unroll
        for (int m = 0; m < 4; m++)
            #pragma unroll
            for (int n = 0; n < 4; n++)
                acc[m + 4][n] = __builtin_amdgcn_mfma_f32_16x16x32_bf16(af[m], bfr[n], acc[m + 4][n], 0, 0, 0);
        __builtin_amdgcn_s_setprio(0);
        asm volatile("" ::: "memory");
        __builtin_amdgcn_s_barrier();   // trailing WAR barrier: reads of ring t&3 consumed
        asm volatile("" ::: "memory");
    }

    int rbase = blockIdx.x * 256 + wm * 128;
    int cbase = blockIdx.y * 256 + wn * 64;
    #pragma unroll
    for (int am = 0; am < 8; am++)
        #pragma unroll
        for (int n = 0; n < 4; n++)
            #pragma unroll
            for (int r = 0; r < 4; r++) {
                int row = rbase + am * 16 + lg * 4 + r;
                int col = cbase + n * 16 + lr;
                float v = acc[am][n][r];
                if (OUTF32) ((float*)Cout)[(size_t)row * N + col] = v;
                else        ((unsigned short*)Cout)[(size_t)row * N + col] = f2bf(v);
            }
}

// ---------------- GEMM: 128x128 m97 structure (kept for gemm2, N=2048) ----------------
template<int OUTF32>
__global__ __launch_bounds__(256) void k_gemm_bt(const unsigned short* __restrict__ A,
                                                 const unsigned short* __restrict__ Bt,
                                                 void* __restrict__ Cout,
                                                 int M, int N, int K) {
    __shared__ unsigned short As[128 * 32];
    __shared__ unsigned short Bs[128 * 32];
    int tid = threadIdx.x;
    int lane = tid & 63;
    int wave = tid >> 6;
    int wm = wave >> 1, wn = wave & 1;
    int lr = lane & 15, lk = (lane >> 4) * 8;
    int srow = wave * 32 + (lane >> 2);
    int scol = (lane & 3) * 8;
    const unsigned short* Ag0 = A  + (size_t)(blockIdx.x * 128 + srow) * K + scol;
    const unsigned short* Ag1 = Ag0 + (size_t)16 * K;
    const unsigned short* Bg0 = Bt + (size_t)(blockIdx.y * 128 + srow) * K + scol;
    const unsigned short* Bg1 = Bg0 + (size_t)16 * K;
    unsigned short* Asw = &As[wave * 1024];
    unsigned short* Bsw = &Bs[wave * 1024];
    f32x4 acc[4][4] = {};
    for (int k0 = 0; k0 < K; k0 += 32) {
        __syncthreads();
        GLL16(Ag0 + k0, Asw);
        GLL16(Ag1 + k0, Asw + 512);
        GLL16(Bg0 + k0, Bsw);
        GLL16(Bg1 + k0, Bsw + 512);
        __syncthreads();
        s16x8 af[4], bfr[4];
        #pragma unroll
        for (int m = 0; m < 4; m++) af[m]  = *(const s16x8*)&As[(wm * 64 + m * 16 + lr) * 32 + lk];
        #pragma unroll
        for (int n = 0; n < 4; n++) bfr[n] = *(const s16x8*)&Bs[(wn * 64 + n * 16 + lr) * 32 + lk];
        #pragma unroll
        for (int m = 0; m < 4; m++)
            #pragma unroll
            for (int n = 0; n < 4; n++)
                acc[m][n] = __builtin_amdgcn_mfma_f32_16x16x32_bf16(af[m], bfr[n], acc[m][n], 0, 0, 0);
    }
    int rbase = blockIdx.x * 128 + wm * 64;
    int cbase = blockIdx.y * 128 + wn * 64;
    #pragma unroll
    for (int m = 0; m < 4; m++)
        #pragma unroll
        for (int n = 0; n < 4; n++)
            #pragma unroll
            for (int r = 0; r < 4; r++) {
                int row = rbase + m * 16 + (lane >> 4) * 4 + r;
                int col = cbase + n * 16 + lr;
                float v = acc[m][n][r];
                if (OUTF32) ((float*)Cout)[(size_t)row * N + col] = v;
                else        ((unsigned short*)Cout)[(size_t)row * N + col] = f2bf(v);
            }
}

// ---------------- fused RMSNorm + RoPE + head transpose (vectorized) ----------------
__global__ __launch_bounds__(256) void k_rms_rope(const unsigned short* __restrict__ qkv,
                                                  const float* __restrict__ qg,
                                                  const float* __restrict__ kg,
                                                  const float* __restrict__ cosc,
                                                  const float* __restrict__ sinc,
                                                  unsigned short* __restrict__ Qt,
                                                  unsigned short* __restrict__ Kt,
                                                  unsigned short* __restrict__ Vt) {
    int r = blockIdx.x;            // b*2048 + s
    int b = r >> 11;
    int s = r & 2047;
    int tid = threadIdx.x;
    int wave = tid >> 6, lane = tid & 63;
    int sl = lane >> 4;            // local segment 0..3
    int li = lane & 15;
    int d0 = li * 8;               // 0..120
    const unsigned short* row = qkv + (size_t)r * 4096;
    #pragma unroll
    for (int p = 0; p < 2; p++) {
        int seg = p * 16 + wave * 4 + sl;   // 0..31, wave-uniform type
        s16x8 raw = *(const s16x8*)(row + seg * 128 + d0);
        if (seg >= 24) {   // V: straight copy (wave-uniform branch)
            *(s16x8*)(Vt + ((size_t)(b * 8 + (seg - 24)) * 2048 + s) * 128 + d0) = raw;
            continue;
        }
        float e[8];
        #pragma unroll
        for (int j = 0; j < 8; j++) e[j] = bf2f((unsigned short)raw[j]);
        float ssq = 0.f;
        #pragma unroll
        for (int j = 0; j < 8; j++) ssq += e[j] * e[j];
        ssq += __shfl_xor(ssq, 1, 64);
        ssq += __shfl_xor(ssq, 2, 64);
        ssq += __shfl_xor(ssq, 4, 64);
        ssq += __shfl_xor(ssq, 8, 64);
        float rn = rsqrtf(ssq * (1.0f / 128.0f) + 1e-6f);
        const float* g = (seg < 16) ? qg : kg;
        float gs = (seg < 16) ? SCALE_L2E : 1.0f;
        float4 g0 = *(const float4*)(g + d0);
        float4 g1 = *(const float4*)(g + d0 + 4);
        float t[8];
        t[0] = e[0] * rn * g0.x * gs; t[1] = e[1] * rn * g0.y * gs;
        t[2] = e[2] * rn * g0.z * gs; t[3] = e[3] * rn * g0.w * gs;
        t[4] = e[4] * rn * g1.x * gs; t[5] = e[5] * rn * g1.y * gs;
        t[6] = e[6] * rn * g1.z * gs; t[7] = e[7] * rn * g1.w * gs;
        float pr[8];
        #pragma unroll
        for (int j = 0; j < 8; j++) pr[j] = __shfl_xor(t[j], 8, 64);
        int didx = d0 & 63;
        float4 c0 = *(const float4*)(cosc + (size_t)s * 64 + didx);
        float4 c1 = *(const float4*)(cosc + (size_t)s * 64 + didx + 4);
        float4 sn0 = *(const float4*)(sinc + (size_t)s * 64 + didx);
        float4 sn1 = *(const float4*)(sinc + (size_t)s * 64 + didx + 4);
        float cv[8] = {c0.x, c0.y, c0.z, c0.w, c1.x, c1.y, c1.z, c1.w};
        float sv[8] = {sn0.x, sn0.y, sn0.z, sn0.w, sn1.x, sn1.y, sn1.z, sn1.w};
        float sgn = (li < 8) ? -1.0f : 1.0f;
        s16x8 o;
        #pragma unroll
        for (int j = 0; j < 8; j++)
            o[j] = (short)f2bf(t[j] * cv[j] + sgn * pr[j] * sv[j]);
        unsigned short* dst = (seg < 16)
            ? Qt + ((size_t)(b * 16 + seg) * 2048 + s) * 128 + d0
            : Kt + ((size_t)(b * 8 + (seg - 16)) * 2048 + s) * 128 + d0;
        *(s16x8*)dst = o;
    }
}

// ---------------- causal GQA flash attention, 32x32 MFMA (R12 version, reverted) ----------------
__global__ __launch_bounds__(256, 2) void k_attn(const unsigned short* __restrict__ Qt,
                                                 const unsigned short* __restrict__ Kt,
                                                 const unsigned short* __restrict__ Vtg,
                                                 unsigned short* __restrict__ attn) {
    __shared__ unsigned short Ks[64][136];     // K tile [kv][d], padded
    __shared__ unsigned short Vs[128][72];     // V^T tile [d][kv], padded
    __shared__ unsigned short Ps[4][32][72];   // per-wave P tile [q][kv], padded
    int bid = blockIdx.x;                  // 0..511
    int lo = bid & 255;
    int qb, bh;
    if (bid < 256) { qb = lo & 15;        bh = lo >> 4; }
    else           { qb = 15 - (lo & 15); bh = 16 + (lo >> 4); }
    int b = bh >> 4, h = bh & 15;
    int kvh = h >> 1;
    int tid = threadIdx.x;
    int lane = tid & 63, wave = tid >> 6;
    int ql = lane & 31;                    // q-local (wave's 32 rows)
    int hf = lane >> 5;                    // half 0/1
    int q0 = qb * 128;
    const unsigned short* Qb    = Qt + ((size_t)bh * 2048 + q0 + wave * 32 + ql) * 128;
    const unsigned short* Kbase = Kt + (size_t)(b * 8 + kvh) * 2048 * 128;
    const unsigned short* Vtb   = Vtg + (size_t)(b * 8 + kvh) * 128 * 2048;   // [d][s]
    s16x8 aq[8];
    #pragma unroll
    for (int ds = 0; ds < 8; ds++)
        aq[ds] = *(const s16x8*)(Qb + ds * 16 + hf * 8);
    f32x16 out[4] = {};
    float m_q = -1e30f, l_q = 0.f;
    int qglob = q0 + wave * 32 + ql;
    int qlo   = q0 + wave * 32;            // wave-uniform bounds
    int qhi   = qlo + 31;
    int ntiles = 2 * qb + 2;
    int krow = tid >> 4, kcol = (tid & 15) * 8;   // K: 16 rows x 128 cols per pass
    int vrow = tid >> 3, vcol = (tid & 7) * 8;    // V^T: 32 rows x 64 cols per pass
    s16x8 kpre[4], vpre[4];
    #pragma unroll
    for (int p = 0; p < 4; p++) {
        kpre[p] = *(const s16x8*)(Kbase + (size_t)(krow + p * 16) * 128 + kcol);
        vpre[p] = *(const s16x8*)(Vtb + (size_t)(vrow + p * 32) * 2048 + vcol);
    }

    for (int t = 0; t < ntiles; t++) {
        int k0 = t * 64;
        __syncthreads();   // previous tile's LDS reads complete
        #pragma unroll
        for (int p = 0; p < 4; p++) {
            *(s16x8*)&Ks[krow + p * 16][kcol] = kpre[p];
            *(s16x8*)&Vs[vrow + p * 32][vcol] = vpre[p];
        }
        __syncthreads();
        if (t + 1 < ntiles) {
            int kn = k0 + 64;
            #pragma unroll
            for (int p = 0; p < 4; p++) {
                kpre[p] = *(const s16x8*)(Kbase + (size_t)(kn + krow + p * 16) * 128 + kcol);
                vpre[p] = *(const s16x8*)(Vtb + (size_t)(vrow + p * 32) * 2048 + kn + vcol);
            }
        }
        if (k0 <= qhi) {
            f32x16 st[2] = {};
            __builtin_amdgcn_s_setprio(1);
            #pragma unroll
            for (int sub = 0; sub < 2; sub++)
                #pragma unroll
                for (int ds = 0; ds < 8; ds++) {
                    s16x8 kf = *(const s16x8*)&Ks[sub * 32 + ql][ds * 16 + hf * 8];
                    st[sub] = __builtin_amdgcn_mfma_f32_32x32x16_bf16(kf, aq[ds], st[sub], 0, 0, 0);
                }
            __builtin_amdgcn_s_setprio(0);
            float mx = -1e30f;
            if (k0 + 63 > qlo) {   // boundary tiles: apply causal mask
                #pragma unroll
                for (int sub = 0; sub < 2; sub++)
                    #pragma unroll
                    for (int r = 0; r < 16; r++) {
                        int kv = k0 + sub * 32 + (r & 3) + 8 * (r >> 2) + 4 * hf;
                        if (kv > qglob) st[sub][r] = -1e30f;
                        mx = fmaxf(mx, st[sub][r]);
                    }
            } else {
                #pragma unroll
                for (int sub = 0; sub < 2; sub++)
                    #pragma unroll
                    for (int r = 0; r < 16; r++) mx = fmaxf(mx, st[sub][r]);
            }
            mx = fmaxf(mx, __shfl_xor(mx, 32, 64));
            bool defer = __all(mx <= m_q + 8.0f);
            float sf = 1.0f;
            if (!defer) {
                float mnew = fmaxf(m_q, mx);
                sf = exp2_fast(m_q - mnew);
                m_q = mnew;
            }
            float rs = 0.f;
            #pragma unroll
            for (int sub = 0; sub < 2; sub++)
                #pragma unroll
                for (int r = 0; r < 16; r++) {
                    float e = exp2_fast(st[sub][r] - m_q);
                    st[sub][r] = e;
                    rs += e;
                }
            rs += __shfl_xor(rs, 32, 64);
            l_q = defer ? (l_q + rs) : (l_q * sf + rs);
            // pack P -> Ps[q][kv] via hardware cvt_pk (RNE)
            #pragma unroll
            for (int sub = 0; sub < 2; sub++)
                #pragma unroll
                for (int g = 0; g < 4; g++) {
                    uint2 w;
                    w.x = cvt_pk_bf16(st[sub][4 * g + 0], st[sub][4 * g + 1]);
                    w.y = cvt_pk_bf16(st[sub][4 * g + 2], st[sub][4 * g + 3]);
                    *(uint2*)&Ps[wave][ql][sub * 32 + g * 8 + hf * 4] = w;
                }
            if (!defer) {
                float sfr[16];
                #pragma unroll
                for (int r = 0; r < 16; r++)
                    sfr[r] = __shfl(sf, (r & 3) + 8 * (r >> 2) + 4 * hf, 64);
                #pragma unroll
                for (int dblk = 0; dblk < 4; dblk++)
                    #pragma unroll
                    for (int r = 0; r < 16; r++) out[dblk][r] *= sfr[r];
            }
            __builtin_amdgcn_s_setprio(1);
            #pragma unroll
            for (int ks = 0; ks < 4; ks++) {
                s16x8 pf = *(const s16x8*)&Ps[wave][ql][ks * 16 + hf * 8];
                #pragma unroll
                for (int dblk = 0; dblk < 4; dblk++) {
                    s16x8 vf = *(const s16x8*)&Vs[dblk * 32 + ql][ks * 16 + hf * 8];
                    out[dblk] = __builtin_amdgcn_mfma_f32_32x32x16_bf16(pf, vf, out[dblk], 0, 0, 0);
                }
            }
            __builtin_amdgcn_s_setprio(0);
        }
    }
    float linv = 1.0f / l_q;
    float inv[16];
    #pragma unroll
    for (int r = 0; r < 16; r++)
        inv[r] = __shfl(linv, (r & 3) + 8 * (r >> 2) + 4 * hf, 64);
    #pragma unroll
    for (int dblk = 0; dblk < 4; dblk++)
        #pragma unroll
        for (int r = 0; r < 16; r++) {
            int row = q0 + wave * 32 + (r & 3) + 8 * (r >> 2) + 4 * hf;
            attn[((size_t)(b * 2048) + row) * 2048 + h * 128 + dblk * 32 + ql] =
                f2bf(out[dblk][r] * inv[r]);
        }
}

extern "C" void kernel_launch(void* const* d_in, const int* in_sizes, int n_in,
                              void* d_out, int out_size, void* d_ws, size_t ws_size,
                              hipStream_t stream) {
    const float* x    = (const float*)d_in[0];
    const float* wq   = (const float*)d_in[1];
    const float* wk   = (const float*)d_in[2];
    const float* wv   = (const float*)d_in[3];
    const float* wo   = (const float*)d_in[4];
    const float* qg   = (const float*)d_in[5];
    const float* kg   = (const float*)d_in[6];
    const float* cosc = (const float*)d_in[7];
    const float* sinc = (const float*)d_in[8];

    char* ws = (char*)d_ws;
    unsigned short* xb   = (unsigned short*)(ws);                 // 16 MiB  x bf16 (4096x2048)
    unsigned short* w1t  = (unsigned short*)(ws + 16777216);      // 16 MiB  [wq|wk|wv]^T (4096x2048)
    unsigned short* w2t  = (unsigned short*)(ws + 33554432);      //  8 MiB  wo^T (2048x2048)
    unsigned short* qkv  = (unsigned short*)(ws + 41943040);      // 32 MiB  (4096x4096); dead after k_rms_rope
    unsigned short* Qt   = (unsigned short*)(ws + 75497472);      // 16 MiB  (2,16,2048,128)
    unsigned short* Kt   = (unsigned short*)(ws + 92274688);      //  8 MiB  (2,8,2048,128)
    unsigned short* Vt   = (unsigned short*)(ws + 100663296);     //  8 MiB  (2,8,2048,128)
    unsigned short* attn = (unsigned short*)(ws + 109051904);     // 16 MiB  (4096x2048)
    unsigned short* Vtg  = qkv;                                   //  8 MiB  (2,8,128,2048) reuses qkv

    k_convert_x<<<4096, 256, 0, stream>>>(x, xb, 8388608);
    k_transpose_w4<<<dim3(64, 64, 4), 256, 0, stream>>>(wq, wk, wv, wo, w1t, w2t);
    k_gemm256<0><<<dim3(16, 16), 512, 0, stream>>>(xb, w1t, qkv, 4096, 4096, 2048);
    k_rms_rope<<<4096, 256, 0, stream>>>(qkv, qg, kg, cosc, sinc, Qt, Kt, Vt);
    k_transpose_v<<<dim3(64, 4, 16), 256, 0, stream>>>(Vt, Vtg);
    k_attn<<<512, 256, 0, stream>>>(Qt, Kt, Vtg, attn);
    k_gemm_bt<1><<<dim3(32, 16), 256, 0, stream>>>(attn, w2t, d_out, 4096, 2048, 2048);
}